// Round 8
// baseline (210.211 us; speedup 1.0000x reference)
//
#include <hip/hip_runtime.h>
#include <math.h>

// MoE router: logits = x[16384,2048] @ W^T[2048,64]; softmax; top-2; renorm.
//
// R13 post-mortem: 7 schedules all give router ~75us. The invariant is VMEM
// WAVE-INSTRUCTION COUNT PER CU at ~100cyc/instr effective service rate
// (x-stream at HBM BW = 1KB/instr at 26GB/s/CU = exactly ~100cyc/instr; the
// model fits R7/R10/R13 within 20%). R13: x 512 + W 1024 instrs/CU = 1536
// -> ~64us. W dominates because every 32-token block re-reads ALL of W.
//
// R14: amortize W 8x -- TPB=256 tokens/block, K split 4 ways (grid 64x4=256,
// 1 block/CU). Block stages its 128KB W-chunk (fp32->fp16 hi/lo split) into
// LDS ONCE (128 instrs), then 8 waves FREE-RUN (no K-loop barriers): wave =
// 32 tok x 64 exp x K512, x fragment-direct from global (read exactly once;
// experts handled by the nt-loop so no cross-wave x redundancy), acc in regs.
// Partials -> LDS transpose (reusing the W region post-barrier) -> coalesced
// float4 stores to workspace [kc][t][e]. Kernel B: sum 4 kc slabs (16MB),
// verified softmax/top-2/renorm epilogue.
// Per-CU vmem instrs: x 512 (HBM floor) + W 128 + stores 64 ~= 704 (2.2x cut).
//
// fp16 split-precision MFMA (verified R5-R13, absmax 0.002): x=xh+xl,
// W=wh+wl, logits = xh*wh + xl*wh + xh*wl, fp32 acc.
// Frag layout (verified): A lane(c=L&15,q=L>>4) = x[tok0+c][q*8..+8];
// B lane(c,q) = W[nt*16+c][q*8..+8]; C/D: token=(L>>4)*4+r, expert=nt*16+c.
//
// wlds layout: [(s*2+hl)*64 + e]*32 + koff  (s=k32 slice 0..15, koff 0..31):
// frag read = 1KB dense per (wave,s,nt,hl) -> conflict-free b128.

typedef _Float16 half8  __attribute__((ext_vector_type(8)));
typedef _Float16 half4  __attribute__((ext_vector_type(4)));
typedef float    floatx4 __attribute__((ext_vector_type(4)));

#define NTOK   16384
#define DDIM   2048
#define NE     64
#define KSPLIT 4
#define KC     512                  // k per chunk
#define PSTRIDE (NTOK * NE)         // floats per kc partial slab (4MB)

__device__ inline void split8(const float4& a, const float4& b,
                              half8& hi, half8& lo) {
    float f[8] = {a.x, a.y, a.z, a.w, b.x, b.y, b.z, b.w};
#pragma unroll
    for (int j = 0; j < 8; ++j) {
        const _Float16 h = (_Float16)f[j];
        hi[j] = h;
        lo[j] = (_Float16)(f[j] - (float)h);
    }
}

__device__ inline void split4(const float4& a, half4& hi, half4& lo) {
    float f[4] = {a.x, a.y, a.z, a.w};
#pragma unroll
    for (int j = 0; j < 4; ++j) {
        const _Float16 h = (_Float16)f[j];
        hi[j] = h;
        lo[j] = (_Float16)(f[j] - (float)h);
    }
}

// ---- kernel A: per-(token-tile, k-chunk) GEMM -> fp32 partials ----
__global__ __launch_bounds__(512, 2) void router_a(
    const float* __restrict__ x,
    const float* __restrict__ W,
    float* __restrict__ partial)
{
    __shared__ __align__(16) _Float16 wlds[65536];   // 128KB W-chunk hi/lo

    const int tid = threadIdx.x;
    const int L   = tid & 63;
    const int wv  = __builtin_amdgcn_readfirstlane(tid >> 6);  // 0..7
    const int c   = L & 15, q = L >> 4;
    const int tile = blockIdx.x & 63;
    const int kc   = blockIdx.x >> 6;          // 0..3
    const int tok_wave = tile * 256 + wv * 32; // wave owns 32 tokens

    // ---- stage W-chunk once: 64 exp x 512 k fp32 -> hi/lo fp16 LDS ----
    // 8192 float4s; thread i covers row e=i>>7, f4 f=i&127 (slice s=f>>3).
#pragma unroll
    for (int r = 0; r < 16; ++r) {
        const int i = r * 512 + tid;
        const int e = i >> 7, f = i & 127;
        const int s = f >> 3, o = f & 7;
        const float4 w4 = *(const float4*)(W + (size_t)e * DDIM + kc * KC + f * 4);
        half4 hi, lo; split4(w4, hi, lo);
        *(half4*)(wlds + ((s * 2 + 0) * 64 + e) * 32 + o * 4) = hi;
        *(half4*)(wlds + ((s * 2 + 1) * 64 + e) * 32 + o * 4) = lo;
    }
    __syncthreads();

    // ---- free-running compute: 16 k32 slices, x prefetch over backedge ----
    floatx4 acc[2][4];
#pragma unroll
    for (int sub = 0; sub < 2; ++sub)
#pragma unroll
        for (int nt = 0; nt < 4; ++nt) acc[sub][nt] = (floatx4)0.f;

    const float* xp0 = x + (size_t)(tok_wave + c) * DDIM + kc * KC + q * 8;
    const float* xp1 = xp0 + 16 * DDIM;        // sub=1 rows

    float4 xc[2][2], xn[2][2];
    xc[0][0] = *(const float4*)(xp0);
    xc[0][1] = *(const float4*)(xp0 + 4);
    xc[1][0] = *(const float4*)(xp1);
    xc[1][1] = *(const float4*)(xp1 + 4);

#pragma unroll 1
    for (int s = 0; s < 16; ++s) {
        if (s + 1 < 16) {                      // crosses backedge: stays live
            xn[0][0] = *(const float4*)(xp0 + (s + 1) * 32);
            xn[0][1] = *(const float4*)(xp0 + (s + 1) * 32 + 4);
            xn[1][0] = *(const float4*)(xp1 + (s + 1) * 32);
            xn[1][1] = *(const float4*)(xp1 + (s + 1) * 32 + 4);
        }
        half8 B[4][2];
#pragma unroll
        for (int nt = 0; nt < 4; ++nt)
#pragma unroll
            for (int hl = 0; hl < 2; ++hl)
                B[nt][hl] = *(const half8*)(wlds + ((s * 2 + hl) * 64 + nt * 16 + c) * 32 + q * 8);
#pragma unroll
        for (int sub = 0; sub < 2; ++sub) {
            half8 Ah, Al;
            split8(xc[sub][0], xc[sub][1], Ah, Al);
#pragma unroll
            for (int nt = 0; nt < 4; ++nt) {
                acc[sub][nt] = __builtin_amdgcn_mfma_f32_16x16x32_f16(Ah, B[nt][0], acc[sub][nt], 0, 0, 0);
                acc[sub][nt] = __builtin_amdgcn_mfma_f32_16x16x32_f16(Al, B[nt][0], acc[sub][nt], 0, 0, 0);
                acc[sub][nt] = __builtin_amdgcn_mfma_f32_16x16x32_f16(Ah, B[nt][1], acc[sub][nt], 0, 0, 0);
            }
        }
        if (s + 1 < 16) {
#pragma unroll
            for (int sub = 0; sub < 2; ++sub)
#pragma unroll
                for (int j = 0; j < 2; ++j) xc[sub][j] = xn[sub][j];
        }
    }

    // ---- epilogue: C-layout -> [t][e] via per-wave LDS scratch ----
    __syncthreads();   // all waves done READING wlds before overwrite
    float* scratch = (float*)wlds + wv * 2048;  // 8KB/wave, 64KB total
#pragma unroll
    for (int sub = 0; sub < 2; ++sub)
#pragma unroll
        for (int nt = 0; nt < 4; ++nt)
#pragma unroll
            for (int r = 0; r < 4; ++r)
                scratch[(sub * 16 + q * 4 + r) * 64 + nt * 16 + c] = acc[sub][nt][r];
    // intra-wave LDS visibility only (compiler inserts lgkm wait)
    float* pp = partial + (size_t)kc * PSTRIDE + (size_t)tok_wave * 64;
#pragma unroll
    for (int it = 0; it < 8; ++it) {
        const int idx = it * 64 + L;           // f4 idx 0..511
        *(float4*)(pp + idx * 4) = *(const float4*)(scratch + idx * 4);
    }
}

// ---- kernel B: reduce 4 kc slabs + softmax + top-2 + renorm ----
__global__ __launch_bounds__(256) void router_b(
    const float* __restrict__ partial,
    float* __restrict__ out)
{
    __shared__ __align__(16) float lg[32 * 68];    // 8.5KB, 68-pad

    const int tid  = threadIdx.x;
    const int btok = blockIdx.x * 32;

    // sum over kc: 32 tok x 64 exp = 512 float4s, 2 per thread
#pragma unroll
    for (int i = 0; i < 2; ++i) {
        const int idx = i * 256 + tid;             // f4 idx 0..511
        const float* p0 = partial + (size_t)btok * 64 + idx * 4;
        const float4 a = *(const float4*)(p0);
        const float4 b = *(const float4*)(p0 + PSTRIDE);
        const float4 cc = *(const float4*)(p0 + 2 * (size_t)PSTRIDE);
        const float4 d = *(const float4*)(p0 + 3 * (size_t)PSTRIDE);
        const int row = idx >> 4, c4 = idx & 15;
        *(float4*)(&lg[row * 68 + c4 * 4]) =
            make_float4(a.x + b.x + cc.x + d.x, a.y + b.y + cc.y + d.y,
                        a.z + b.z + cc.z + d.z, a.w + b.w + cc.w + d.w);
    }
    __syncthreads();

    // ---- softmax + top-2: thread t < 32 owns token btok+t (verified) ----
    if (tid < 32) {
        const int token = btok + tid;
        float* row = &lg[tid * 68];
        float pr[NE];
#pragma unroll
        for (int e = 0; e < NE; ++e) pr[e] = row[e];

        float m = pr[0];
#pragma unroll
        for (int e = 1; e < NE; ++e) m = fmaxf(m, pr[e]);
        float s = 0.f;
#pragma unroll
        for (int e = 0; e < NE; ++e) { pr[e] = expf(pr[e] - m); s += pr[e]; }
        const float inv = 1.f / s;

        // lax.top_k tie-break = lowest index first -> strict '>' ascending scan
        float v1 = -1.f; int i1 = 0;
#pragma unroll
        for (int e = 0; e < NE; ++e) { if (pr[e] > v1) { v1 = pr[e]; i1 = e; } }
        float v2 = -1.f; int i2 = 0;
#pragma unroll
        for (int e = 0; e < NE; ++e) { if (e != i1 && pr[e] > v2) { v2 = pr[e]; i2 = e; } }

        const float ts = v1 + v2;
        float* out_tp = out;              // top_k_probs  [NTOK][2]
        float* out_ti = out + 2 * NTOK;   // top_k_indices[NTOK][2] (float values)
        *(float2*)(out_tp + token * 2) = make_float2(v1 / ts, v2 / ts);
        *(float2*)(out_ti + token * 2) = make_float2((float)i1, (float)i2);

#pragma unroll
        for (int e = 0; e < NE; ++e) row[e] = pr[e] * inv;
    }
    __syncthreads();

    // ---- cooperative coalesced probs write: 32 tok x 64 = 2048 floats ----
    {
        float* out_p = out + 4 * NTOK + (size_t)btok * NE;
#pragma unroll
        for (int i = 0; i < 2; ++i) {
            const int f = tid + 256 * i;        // float4 idx, 512 total
            const int r = f >> 4, c4 = f & 15;
            const float4 v = *(const float4*)&lg[r * 68 + 4 * c4];
            *(float4*)(out_p + f * 4) = v;
        }
    }
}

extern "C" void kernel_launch(void* const* d_in, const int* in_sizes, int n_in,
                              void* d_out, int out_size, void* d_ws, size_t ws_size,
                              hipStream_t stream) {
    const float* x = (const float*)d_in[0];
    const float* W = (const float*)d_in[1];
    float* out     = (float*)d_out;
    float* pp      = (float*)d_ws;   // 16MB: partial[kc][token][expert]

    router_a<<<dim3(64 * KSPLIT), dim3(512), 0, stream>>>(x, W, pp);
    router_b<<<dim3(NTOK / 32), dim3(256), 0, stream>>>(pp, out);
}